// Round 6
// baseline (648.110 us; speedup 1.0000x reference)
//
#include <hip/hip_runtime.h>

typedef unsigned short u16;
typedef unsigned int u32;
typedef __bf16 bf16x8 __attribute__((ext_vector_type(8)));
typedef float f32x4 __attribute__((ext_vector_type(4)));
typedef unsigned short u16x8 __attribute__((ext_vector_type(8)));
typedef unsigned int u32x4 __attribute__((ext_vector_type(4)));
typedef _Float16 v2h __attribute__((ext_vector_type(2)));

__device__ __forceinline__ u16 f2bf(float f) {
    unsigned u = __float_as_uint(f);
    u = (u + 0x7fffu + ((u >> 16) & 1u)) >> 16;
    return (u16)u;
}
__device__ __forceinline__ float bf2f(u16 h) {
    return __uint_as_float((unsigned)h << 16);
}
__device__ __forceinline__ u32 packh2(float a, float b) {
    _Float16 ha = (_Float16)a, hb = (_Float16)b;
    u16 la = __builtin_bit_cast(u16, ha), lb = __builtin_bit_cast(u16, hb);
    return (u32)la | ((u32)lb << 16);
}
__device__ __forceinline__ float dot2acc(u32 w, u32 h, float acc) {
#if __has_builtin(__builtin_amdgcn_fdot2)
    return __builtin_amdgcn_fdot2(__builtin_bit_cast(v2h, w),
                                  __builtin_bit_cast(v2h, h), acc, false);
#else
    v2h wv = __builtin_bit_cast(v2h, w), hv = __builtin_bit_cast(v2h, h);
    return acc + (float)wv.x * (float)hv.x + (float)wv.y * (float)hv.y;
#endif
}
__device__ __forceinline__ float dot8(u32x4 w, u32x4 h, float acc) {
    acc = dot2acc(w.x, h.x, acc);
    acc = dot2acc(w.y, h.y, acc);
    acc = dot2acc(w.z, h.z, acc);
    acc = dot2acc(w.w, h.w, acc);
    return acc;
}
__device__ __forceinline__ void gload_lds16(const void* g, void* l) {
    __builtin_amdgcn_global_load_lds(
        (const __attribute__((address_space(1))) unsigned int*)g,
        (__attribute__((address_space(3))) unsigned int*)l, 16, 0, 0);
}

// ---------------------------------------------------------------------------
// prep+fconv fused. Blocks [0,3924): weight prep; blocks [3924,13332): frames
// fp32->bf16 nt-store (big path only).
// ---------------------------------------------------------------------------
__global__ __launch_bounds__(256) void prep_kernel(
    const float* __restrict__ cnn_w, const float* __restrict__ cnn1_w,
    const float* __restrict__ w_hh, const float* __restrict__ w_ih,
    const float* __restrict__ fi_w, const float* __restrict__ frames,
    u16* __restrict__ B1, u16* __restrict__ B2,
    u32* __restrict__ whh8, u32* __restrict__ wih8, u32* __restrict__ fi8,
    u32* __restrict__ zpage, u16* __restrict__ fbf)
{
    if (blockIdx.x >= 3924) {
        size_t i = ((size_t)(blockIdx.x - 3924) * 256 + threadIdx.x) * 8;
        float4 a = *(const float4*)(frames + i);
        float4 b = *(const float4*)(frames + i + 4);
        u16x8 v = { f2bf(a.x), f2bf(a.y), f2bf(a.z), f2bf(a.w),
                    f2bf(b.x), f2bf(b.y), f2bf(b.z), f2bf(b.w) };
        __builtin_nontemporal_store(v, (u16x8*)(fbf + i));
        return;
    }
    int idx = blockIdx.x * 256 + threadIdx.x;
    if (idx < 442368) { B1[idx] = f2bf(cnn_w[idx]); return; }
    idx -= 442368;
    if (idx < 331776) {
        int n = idx / 5184, rem = idx - n * 5184;
        int off = rem / 576, c = rem - off * 576;
        int dy = off / 3, dx = off - dy * 3;
        B2[idx] = f2bf(cnn1_w[((n * 576 + c) * 3 + dy) * 3 + dx]);
        return;
    }
    idx -= 331776;
    if (idx < 98304) {
        int kb = idx / 3072, r = idx - kb * 3072;
        int o = r >> 2, c = r & 3;
        int kk = kb * 8 + c * 2;
        whh8[idx] = packh2(w_hh[o * 256 + kk], w_hh[o * 256 + kk + 1]);
        return;
    }
    idx -= 98304;
    if (idx < 98304) {
        int kb = idx / 3072, r = idx - kb * 3072;
        int o = r >> 2, c = r & 3;
        int kk = kb * 8 + c * 2;
        wih8[idx] = packh2(w_ih[o * 256 + kk], w_ih[o * 256 + kk + 1]);
        return;
    }
    idx -= 98304;
    if (idx < 32768) {
        int kb = idx / 1024, r = idx - kb * 1024;
        int u = r >> 2, c = r & 3;
        int kk = kb * 8 + c * 2;
        fi8[idx] = packh2(fi_w[u * 256 + kk], fi_w[u * 256 + kk + 1]);
        return;
    }
    idx -= 32768;
    if (idx < 1024) zpage[idx] = 0u;
}

// ---------------------------------------------------------------------------
// GEMM1 v3: patchify conv, BM=128, BN=192, BK=64. grid = 196*3 = 588.
// global_load_lds(16B) staging with source-side XOR swizzle.
// ---------------------------------------------------------------------------
__global__ __launch_bounds__(256) void gemm1_v3(
    const u16* __restrict__ fbf, const u16* __restrict__ B1,
    const float* __restrict__ cnn_b, u16* __restrict__ f1)
{
    __shared__ u16 As[128 * 64];
    __shared__ u16 Bs[192 * 64];
    const int t = threadIdx.x, bx = blockIdx.x;
    const int m0 = (bx / 3) * 128, n0 = (bx % 3) * 192;
    const int wave = t >> 6, lane = t & 63;
    const int lm = lane & 15, lq = lane >> 4;

    f32x4 acc[2][12];
#pragma unroll
    for (int i = 0; i < 2; ++i)
#pragma unroll
        for (int q = 0; q < 12; ++q) acc[i][q] = (f32x4){0.f, 0.f, 0.f, 0.f};

    int ac8[4]; size_t abase[4];
#pragma unroll
    for (int i = 0; i < 4; ++i) {
        int s = wave * 256 + i * 64 + lane;
        int row = s >> 3, cc = s & 7;
        ac8[i] = cc ^ (row & 7);
        int m = m0 + row;
        int fr = m / 49, pos = m - fr * 49;
        int py = pos / 7, px = pos - py * 7;
        abase[i] = (size_t)fr * 37632 + py * 1792 + px * 16;
    }
    int bn[6], bc8[6];
#pragma unroll
    for (int i = 0; i < 6; ++i) {
        int s = wave * 384 + i * 64 + lane;
        int n = s >> 3, cc = s & 7;
        bn[i] = n; bc8[i] = cc ^ (n & 7);
    }

    for (int kt = 0; kt < 12; ++kt) {
        const int k0 = kt * 64;
#pragma unroll
        for (int i = 0; i < 4; ++i) {
            int k = k0 + ac8[i] * 8;
            int c = k >> 8, dy = (k >> 4) & 15, dx = k & 15;
            gload_lds16(fbf + abase[i] + c * 12544 + dy * 112 + dx,
                        &As[(wave * 256 + i * 64) * 8]);
        }
#pragma unroll
        for (int i = 0; i < 6; ++i) {
            gload_lds16(B1 + (size_t)(n0 + bn[i]) * 768 + k0 + bc8[i] * 8,
                        &Bs[(wave * 384 + i * 64) * 8]);
        }
        __syncthreads();
#pragma unroll
        for (int s = 0; s < 2; ++s) {
            int c8 = s * 4 + lq;
            bf16x8 a[2];
#pragma unroll
            for (int mi = 0; mi < 2; ++mi) {
                int row = wave * 32 + mi * 16 + lm;
                a[mi] = *(const bf16x8*)(&As[(row * 8 + (c8 ^ (row & 7))) * 8]);
            }
#pragma unroll
            for (int q = 0; q < 12; ++q) {
                int n = q * 16 + lm;
                bf16x8 b = *(const bf16x8*)(&Bs[(n * 8 + (c8 ^ (n & 7))) * 8]);
#pragma unroll
                for (int mi = 0; mi < 2; ++mi)
                    acc[mi][q] = __builtin_amdgcn_mfma_f32_16x16x32_bf16(a[mi], b, acc[mi][q], 0, 0, 0);
            }
        }
        __syncthreads();
    }
#pragma unroll
    for (int mi = 0; mi < 2; ++mi) {
#pragma unroll
        for (int q = 0; q < 12; ++q) {
            int n = n0 + q * 16 + lm;
            float bias = cnn_b[n];
#pragma unroll
            for (int r = 0; r < 4; ++r) {
                int m = m0 + wave * 32 + mi * 16 + lq * 4 + r;
                __builtin_nontemporal_store(f2bf(acc[mi][q][r] + bias), &f1[(size_t)m * 576 + n]);
            }
        }
    }
}

// ---------------------------------------------------------------------------
// GEMM1 legacy (small ws): VALU-cvt staging from fp32 frames. grid = 196*9.
// ---------------------------------------------------------------------------
__global__ __launch_bounds__(256) void gemm1_patchify(
    const float* __restrict__ frames, const u16* __restrict__ B1,
    const float* __restrict__ cnn_b, u16* __restrict__ f1)
{
    __shared__ u16 As[128 * 64];
    __shared__ u16 Bs[64 * 64];
    const int t = threadIdx.x;
    const int bx = blockIdx.x;
    const int m0 = (bx / 9) * 128;
    const int n0 = (bx % 9) * 64;
    const int wave = t >> 6, lane = t & 63;
    const int lm = lane & 15, lq = lane >> 4;

    f32x4 acc[2][4];
#pragma unroll
    for (int i = 0; i < 2; ++i)
#pragma unroll
        for (int q = 0; q < 4; ++q) acc[i][q] = (f32x4){0.f, 0.f, 0.f, 0.f};

    int arow[4], ac8[4], abase[4];
#pragma unroll
    for (int i = 0; i < 4; ++i) {
        int cid = t + i * 256;
        int row = cid >> 3, c8 = cid & 7;
        int m = m0 + row;
        int fr = m / 49, pos = m - fr * 49;
        int py = pos / 7, px = pos - py * 7;
        arow[i] = row; ac8[i] = c8;
        abase[i] = (fr * 3 * 112 + py * 16) * 112 + px * 16;
    }

    for (int kt = 0; kt < 12; ++kt) {
        const int k0 = kt * 64;
#pragma unroll
        for (int i = 0; i < 4; ++i) {
            int k = k0 + ac8[i] * 8;
            int c = k >> 8, dy = (k >> 4) & 15, dx = k & 15;
            const float* src = frames + abase[i] + (c * 112 + dy) * 112 + dx;
            float4 v0 = *(const float4*)src;
            float4 v1 = *(const float4*)(src + 4);
            u16x8 v = { f2bf(v0.x), f2bf(v0.y), f2bf(v0.z), f2bf(v0.w),
                        f2bf(v1.x), f2bf(v1.y), f2bf(v1.z), f2bf(v1.w) };
            int sidx = arow[i] * 8 + (ac8[i] ^ (arow[i] & 7));
            *(u16x8*)(&As[sidx * 8]) = v;
        }
#pragma unroll
        for (int i = 0; i < 2; ++i) {
            int cid = t + i * 256;
            int n = cid >> 3, c8 = cid & 7;
            u16x8 v = *(const u16x8*)(B1 + (size_t)(n0 + n) * 768 + k0 + c8 * 8);
            int sidx = n * 8 + (c8 ^ (n & 7));
            *(u16x8*)(&Bs[sidx * 8]) = v;
        }
        __syncthreads();
#pragma unroll
        for (int s = 0; s < 2; ++s) {
            bf16x8 a[2], b[4];
#pragma unroll
            for (int mi = 0; mi < 2; ++mi) {
                int row = wave * 32 + mi * 16 + lm;
                int c8 = s * 4 + lq;
                a[mi] = *(const bf16x8*)(&As[(row * 8 + (c8 ^ (row & 7))) * 8]);
            }
#pragma unroll
            for (int q = 0; q < 4; ++q) {
                int n = q * 16 + lm;
                int c8 = s * 4 + lq;
                b[q] = *(const bf16x8*)(&Bs[(n * 8 + (c8 ^ (n & 7))) * 8]);
            }
#pragma unroll
            for (int mi = 0; mi < 2; ++mi)
#pragma unroll
                for (int q = 0; q < 4; ++q)
                    acc[mi][q] = __builtin_amdgcn_mfma_f32_16x16x32_bf16(a[mi], b[q], acc[mi][q], 0, 0, 0);
        }
        __syncthreads();
    }
#pragma unroll
    for (int mi = 0; mi < 2; ++mi) {
#pragma unroll
        for (int q = 0; q < 4; ++q) {
            int n = n0 + q * 16 + lm;
            float bias = cnn_b[n];
#pragma unroll
            for (int r = 0; r < 4; ++r) {
                int m = m0 + wave * 32 + mi * 16 + lq * 4 + r;
                __builtin_nontemporal_store(f2bf(acc[mi][q][r] + bias), &f1[(size_t)m * 576 + n]);
            }
        }
    }
}

// ---------------------------------------------------------------------------
// GEMM2 v2: 3x3 SAME conv, 9-offset implicit GEMM. BM=64, full K=5184.
// global_load_lds staging, zero-page for halo. grid = 392.
// ---------------------------------------------------------------------------
__global__ __launch_bounds__(256) void gemm2_v2(
    const u16* __restrict__ f1, const u16* __restrict__ B2,
    const u16* __restrict__ zpage, float* __restrict__ C2)
{
    __shared__ u16 As[64 * 64];
    __shared__ u16 Bs[64 * 64];
    const int t = threadIdx.x;
    const int m0 = blockIdx.x * 64;
    const int wave = t >> 6, lane = t & 63;
    const int lm = lane & 15, lq = lane >> 4;

    f32x4 acc[4];
#pragma unroll
    for (int q = 0; q < 4; ++q) acc[q] = (f32x4){0.f, 0.f, 0.f, 0.f};

    int ac8[2], afr[2], apy[2], apx[2];
#pragma unroll
    for (int i = 0; i < 2; ++i) {
        int s = wave * 128 + i * 64 + lane;
        int row = s >> 3, cc = s & 7;
        ac8[i] = cc ^ (row & 7);
        int m = m0 + row;
        int fr = m / 49, pos = m - fr * 49;
        int py = pos / 7;
        afr[i] = fr; apy[i] = py; apx[i] = pos - py * 7;
    }
    int bn[2], bc8[2];
#pragma unroll
    for (int i = 0; i < 2; ++i) {
        int s = wave * 128 + i * 64 + lane;
        int n = s >> 3, cc = s & 7;
        bn[i] = n; bc8[i] = cc ^ (n & 7);
    }

    for (int kt = 0; kt < 81; ++kt) {
        int off = kt / 9, cb = kt - off * 9;
        int dy = off / 3, dx = off - dy * 3;
        int c0 = cb * 64;
#pragma unroll
        for (int i = 0; i < 2; ++i) {
            int yy = apy[i] + dy - 1, xx = apx[i] + dx - 1;
            const u16* g = ((unsigned)yy < 7u && (unsigned)xx < 7u)
                ? f1 + ((size_t)(afr[i] * 49 + yy * 7 + xx)) * 576 + c0 + ac8[i] * 8
                : zpage;
            gload_lds16(g, &As[(wave * 128 + i * 64) * 8]);
        }
#pragma unroll
        for (int i = 0; i < 2; ++i) {
            gload_lds16(B2 + (size_t)bn[i] * 5184 + kt * 64 + bc8[i] * 8,
                        &Bs[(wave * 128 + i * 64) * 8]);
        }
        __syncthreads();
#pragma unroll
        for (int s = 0; s < 2; ++s) {
            int row = wave * 16 + lm;
            int c8 = s * 4 + lq;
            bf16x8 a = *(const bf16x8*)(&As[(row * 8 + (c8 ^ (row & 7))) * 8]);
            bf16x8 b[4];
#pragma unroll
            for (int q = 0; q < 4; ++q) {
                int n = q * 16 + lm;
                b[q] = *(const bf16x8*)(&Bs[(n * 8 + (c8 ^ (n & 7))) * 8]);
            }
#pragma unroll
            for (int q = 0; q < 4; ++q)
                acc[q] = __builtin_amdgcn_mfma_f32_16x16x32_bf16(a, b[q], acc[q], 0, 0, 0);
        }
        __syncthreads();
    }
#pragma unroll
    for (int q = 0; q < 4; ++q)
#pragma unroll
        for (int r = 0; r < 4; ++r) {
            int m = m0 + wave * 16 + lq * 4 + r;
            int n = q * 16 + lm;
            __builtin_nontemporal_store(acc[q][r], &C2[(size_t)m * 64 + n]);
        }
}

// ---------------------------------------------------------------------------
// reduce: fmean[bl][ch] = BN( mean_p relu(C2[bl*49+p][ch] + cnn1_b[ch]) )
// ---------------------------------------------------------------------------
__global__ __launch_bounds__(256) void reduce_kernel(
    const float* __restrict__ C2, const float* __restrict__ cnn1_b,
    const float* __restrict__ bn_g, const float* __restrict__ bn_b,
    const float* __restrict__ bn_m, const float* __restrict__ bn_v,
    float* __restrict__ fmean)
{
    int idx = blockIdx.x * 256 + threadIdx.x;
    int bl = idx >> 6, ch = idx & 63;
    float bias = cnn1_b[ch];
    const float* p = C2 + (size_t)bl * 49 * 64 + ch;
    float s = 0.f;
#pragma unroll
    for (int i = 0; i < 49; ++i) s += fmaxf(p[i * 64] + bias, 0.f);
    float mean = s * (1.f / 49.f);
    float inv = bn_g[ch] * rsqrtf(bn_v[ch] + 1e-5f);
    fmean[idx] = (mean - bn_m[ch]) * inv + bn_b[ch];
}

// ---------------------------------------------------------------------------
// adapter + prep2 fused. Blocks [0,512): adapter per (b,l). Blocks [512,1280):
// wih hi/lo split for gi_kernel.
// ---------------------------------------------------------------------------
__global__ __launch_bounds__(256) void adapt_prep2_kernel(
    const float* __restrict__ x, const float* __restrict__ fmean,
    const float* __restrict__ a0_w, const float* __restrict__ a0_b,
    const float* __restrict__ ai_w, const float* __restrict__ ai_b,
    const float* __restrict__ an_w, const float* __restrict__ an_b,
    const float* __restrict__ w_ih,
    u16* __restrict__ zx_hi, u16* __restrict__ zx_lo,
    u16* __restrict__ wih_hi, u16* __restrict__ wih_lo)
{
    const int t = threadIdx.x;
    if (blockIdx.x >= 512) {
        int idx = (blockIdx.x - 512) * 256 + t;
        float v = w_ih[idx];
        u16 hi = f2bf(v);
        wih_hi[idx] = hi;
        wih_lo[idx] = f2bf(v - bf2f(hi));
        return;
    }
    const int bl = blockIdx.x;
    __shared__ float s0[16];
    __shared__ float sf[80];
    if (t < 16) {
        float a = a0_b[t];
        const float* xp = x + bl * 12;
#pragma unroll
        for (int i = 0; i < 12; ++i) a += xp[i] * a0_w[t * 12 + i];
        s0[t] = fmaxf(a, 0.f);
    }
    __syncthreads();
    if (t < 16) {
        float a = ai_b[t];
#pragma unroll
        for (int i = 0; i < 16; ++i) a += s0[i] * ai_w[t * 16 + i];
        sf[t] = s0[t] + fmaxf(a, 0.f);
    } else if (t < 80) {
        sf[t] = fmean[bl * 64 + (t - 16)];
    }
    __syncthreads();
    float a = an_b[t];
#pragma unroll 8
    for (int i = 0; i < 80; ++i) a += sf[i] * an_w[t * 80 + i];
    a = fmaxf(a, 0.f);
    u16 hi = f2bf(a);
    zx_hi[bl * 256 + t] = hi;
    zx_lo[bl * 256 + t] = f2bf(a - bf2f(hi));
}

// ---------------------------------------------------------------------------
// gi_pre = zx @ w_ih^T + b_ih via hi/lo bf16 MFMA. M=512,N=768,K=256. grid=48
// ---------------------------------------------------------------------------
__global__ __launch_bounds__(256) void gi_kernel(
    const u16* __restrict__ zx_hi, const u16* __restrict__ zx_lo,
    const u16* __restrict__ wih_hi, const u16* __restrict__ wih_lo,
    const float* __restrict__ b_ih, float* __restrict__ gi_pre)
{
    __shared__ u16 Ah[128 * 64], Al[128 * 64];
    __shared__ u16 Bh[64 * 64], Bl[64 * 64];
    const int t = threadIdx.x, bx = blockIdx.x;
    const int m0 = (bx / 12) * 128, n0 = (bx % 12) * 64;
    const int wave = t >> 6, lane = t & 63;
    const int lm = lane & 15, lq = lane >> 4;

    f32x4 acc[2][4];
#pragma unroll
    for (int i = 0; i < 2; ++i)
#pragma unroll
        for (int q = 0; q < 4; ++q) acc[i][q] = (f32x4){0.f, 0.f, 0.f, 0.f};

    for (int kt = 0; kt < 4; ++kt) {
        const int k0 = kt * 64;
#pragma unroll
        for (int i = 0; i < 4; ++i) {
            int cid = t + i * 256;
            int row = cid >> 3, c8 = cid & 7;
            size_t src = (size_t)(m0 + row) * 256 + k0 + c8 * 8;
            int sidx = (row * 8 + (c8 ^ (row & 7))) * 8;
            *(u16x8*)(&Ah[sidx]) = *(const u16x8*)(zx_hi + src);
            *(u16x8*)(&Al[sidx]) = *(const u16x8*)(zx_lo + src);
        }
#pragma unroll
        for (int i = 0; i < 2; ++i) {
            int cid = t + i * 256;
            int n = cid >> 3, c8 = cid & 7;
            size_t src = (size_t)(n0 + n) * 256 + k0 + c8 * 8;
            int sidx = (n * 8 + (c8 ^ (n & 7))) * 8;
            *(u16x8*)(&Bh[sidx]) = *(const u16x8*)(wih_hi + src);
            *(u16x8*)(&Bl[sidx]) = *(const u16x8*)(wih_lo + src);
        }
        __syncthreads();
#pragma unroll
        for (int s = 0; s < 2; ++s) {
            bf16x8 ah[2], al[2], bh[4], blv[4];
#pragma unroll
            for (int mi = 0; mi < 2; ++mi) {
                int row = wave * 32 + mi * 16 + lm;
                int c8 = s * 4 + lq;
                int sidx = (row * 8 + (c8 ^ (row & 7))) * 8;
                ah[mi] = *(const bf16x8*)(&Ah[sidx]);
                al[mi] = *(const bf16x8*)(&Al[sidx]);
            }
#pragma unroll
            for (int q = 0; q < 4; ++q) {
                int n = q * 16 + lm;
                int c8 = s * 4 + lq;
                int sidx = (n * 8 + (c8 ^ (n & 7))) * 8;
                bh[q] = *(const bf16x8*)(&Bh[sidx]);
                blv[q] = *(const bf16x8*)(&Bl[sidx]);
            }
#pragma unroll
            for (int mi = 0; mi < 2; ++mi)
#pragma unroll
                for (int q = 0; q < 4; ++q) {
                    acc[mi][q] = __builtin_amdgcn_mfma_f32_16x16x32_bf16(ah[mi], bh[q], acc[mi][q], 0, 0, 0);
                    acc[mi][q] = __builtin_amdgcn_mfma_f32_16x16x32_bf16(ah[mi], blv[q], acc[mi][q], 0, 0, 0);
                    acc[mi][q] = __builtin_amdgcn_mfma_f32_16x16x32_bf16(al[mi], bh[q], acc[mi][q], 0, 0, 0);
                }
        }
        __syncthreads();
    }
#pragma unroll
    for (int q = 0; q < 4; ++q) {
        int n = n0 + q * 16 + lm;
        float bias = b_ih[n];
#pragma unroll
        for (int mi = 0; mi < 2; ++mi)
#pragma unroll
            for (int r = 0; r < 4; ++r) {
                int m = m0 + wave * 32 + mi * 16 + lq * 4 + r;
                gi_pre[(size_t)m * 768 + n] = acc[mi][q][r] + bias;
            }
    }
}

// ---------------------------------------------------------------------------
// rnn_stream3: 32 blocks x 768 threads. 144KB w_hh pinned in dynamic LDS;
// streamed weights hoisted into register batches before the dot chains;
// dual accumulators split the fdot2 dependency chain.
// ---------------------------------------------------------------------------
__global__ __launch_bounds__(768) void rnn_stream3(
    const float* __restrict__ gi_pre,
    const u32x4* __restrict__ whh8, const u32x4* __restrict__ wih8,
    const u32x4* __restrict__ fi8,
    const float* __restrict__ b_ih, const float* __restrict__ b_hh,
    const float* __restrict__ fi_b,
    const float* __restrict__ fn_w, const float* __restrict__ fn_b,
    float* __restrict__ out)
{
    extern __shared__ __align__(16) u32 slab[];   // 12*768*16B = 147456 B
    const int b = blockIdx.x, t = threadIdx.x;
    const int wave = t >> 6;
    __shared__ __align__(16) u32 h2[128];
    __shared__ __align__(16) u32 x2[128];
    __shared__ float sA[768];
    __shared__ float sB[256];
    __shared__ float parts[768];
    __shared__ float pp[8];

#pragma unroll
    for (int j = 0; j < 12; ++j)
        *(u32x4*)&slab[(j * 768 + t) * 4] = whh8[j * 768 + t];

    const float bhh = b_hh[t];
    const float bih = b_ih[t];
    float hprev = 0.f;
    if (t < 128) h2[t] = 0u;

    // streamed whh indices (kb 12..31, per-wave phase rotation)
    int sjj[20];
#pragma unroll
    for (int j = 0; j < 20; ++j) {
        int jj = j + wave; if (jj >= 20) jj -= 20;
        sjj[j] = 12 + jj;
    }
    __syncthreads();

    // ===================== encoder: 16 steps =====================
    for (int l = 0; l < 16; ++l) {
        float gi = gi_pre[(size_t)(b * 16 + l) * 768 + t];
        // hoist all 20 streamed weights first (deep load pipeline)
        u32x4 w[20];
#pragma unroll
        for (int j = 0; j < 20; ++j)
            w[j] = whh8[(size_t)sjj[j] * 768 + t];
        float a0 = 0.f, a1 = 0.f;
#pragma unroll
        for (int j = 0; j < 12; ++j) {
            u32x4 ws = *(const u32x4*)&slab[(j * 768 + t) * 4];
            u32x4 hh = *(const u32x4*)&h2[j * 4];
            if (j & 1) a1 = dot8(ws, hh, a1); else a0 = dot8(ws, hh, a0);
        }
#pragma unroll
        for (int j = 0; j < 20; ++j) {
            u32x4 hh = *(const u32x4*)&h2[sjj[j] * 4];
            if (j & 1) a1 = dot8(w[j], hh, a1); else a0 = dot8(w[j], hh, a0);
        }
        float ah = a0 + a1;
        if (t < 512) sA[t] = gi + ah + bhh;
        else { sA[t] = gi; sB[t - 512] = ah + bhh; }
        __syncthreads();
        if (t < 256) {
            float r = 1.f / (1.f + expf(-sA[t]));
            float z = 1.f / (1.f + expf(-sA[256 + t]));
            float n = tanhf(sA[512 + t] + r * sB[t]);
            hprev = (1.f - z) * n + z * hprev;
            float partner = __shfl_xor(hprev, 1);
            if ((t & 1) == 0) h2[t >> 1] = packh2(hprev, partner);
        }
        __syncthreads();
    }

    // ===================== decoder: 10 steps =====================
    float xprev = hprev;
    if (t < 128) x2[t] = h2[t];
    __syncthreads();

    for (int d = 0; d < 10; ++d) {
        float a0 = 0.f, a1 = 0.f, x0 = 0.f, x1 = 0.f;
        // group 1: 10 streamed whh
        {
            u32x4 w[10];
#pragma unroll
            for (int j = 0; j < 10; ++j) w[j] = whh8[(size_t)sjj[j] * 768 + t];
#pragma unroll
            for (int j = 0; j < 10; ++j) {
                u32x4 hh = *(const u32x4*)&h2[sjj[j] * 4];
                if (j & 1) a1 = dot8(w[j], hh, a1); else a0 = dot8(w[j], hh, a0);
            }
        }
        // group 2: 10 streamed whh
        {
            u32x4 w[10];
#pragma unroll
            for (int j = 0; j < 10; ++j) w[j] = whh8[(size_t)sjj[10 + j] * 768 + t];
#pragma unroll
            for (int j = 0; j < 10; ++j) {
                u32x4 hh = *(const u32x4*)&h2[sjj[10 + j] * 4];
                if (j & 1) a1 = dot8(w[j], hh, a1); else a0 = dot8(w[j], hh, a0);
            }
        }
        // pinned 12 whh
#pragma unroll
        for (int j = 0; j < 12; ++j) {
            u32x4 ws = *(const u32x4*)&slab[(j * 768 + t) * 4];
            u32x4 hh = *(const u32x4*)&h2[j * 4];
            if (j & 1) a1 = dot8(ws, hh, a1); else a0 = dot8(ws, hh, a0);
        }
        // wih stream: 2 groups of 16, wave-rotated
        {
            u32x4 w[16];
#pragma unroll
            for (int j = 0; j < 16; ++j) {
                int jj = (j + wave * 3) & 31;
                w[j] = wih8[(size_t)jj * 768 + t];
            }
#pragma unroll
            for (int j = 0; j < 16; ++j) {
                int jj = (j + wave * 3) & 31;
                u32x4 xx = *(const u32x4*)&x2[jj * 4];
                if (j & 1) x1 = dot8(w[j], xx, x1); else x0 = dot8(w[j], xx, x0);
            }
        }
        {
            u32x4 w[16];
#pragma unroll
            for (int j = 0; j < 16; ++j) {
                int jj = (16 + j + wave * 3) & 31;
                w[j] = wih8[(size_t)jj * 768 + t];
            }
#pragma unroll
            for (int j = 0; j < 16; ++j) {
                int jj = (16 + j + wave * 3) & 31;
                u32x4 xx = *(const u32x4*)&x2[jj * 4];
                if (j & 1) x1 = dot8(w[j], xx, x1); else x0 = dot8(w[j], xx, x0);
            }
        }
        float ah = a0 + a1, ax = x0 + x1;
        if (t < 512) sA[t] = ax + bih + ah + bhh;
        else { sA[t] = ax + bih; sB[t - 512] = ah + bhh; }
        __syncthreads();
        if (t < 256) {
            float r = 1.f / (1.f + expf(-sA[t]));
            float z = 1.f / (1.f + expf(-sA[256 + t]));
            float n = tanhf(sA[512 + t] + r * sB[t]);
            hprev = (1.f - z) * n + z * hprev;
            float partner = __shfl_xor(hprev, 1);
            if ((t & 1) == 0) h2[t >> 1] = packh2(hprev, partner);
        }
        __syncthreads();
        // fi matvec over all 12 waves: unit u = t&255, k-slice s = t>>8
        {
            int u = t & 255, s = t >> 8;
            u32x4 w[11];
            int cnt = 0;
#pragma unroll
            for (int j = 0; j < 11; ++j) {
                int jj = s + j * 3;
                if (jj < 32) { w[j] = fi8[jj * 256 + u]; cnt = j + 1; }
            }
            float f0 = 0.f, f1v = 0.f;
            for (int j = 0; j < cnt; ++j) {
                int jj = s + j * 3;
                u32x4 hh = *(const u32x4*)&h2[jj * 4];
                if (j & 1) f1v = dot8(w[j], hh, f1v); else f0 = dot8(w[j], hh, f0);
            }
            parts[t] = f0 + f1v;
        }
        __syncthreads();
        if (t < 256) {
            float a = parts[t] + parts[256 + t] + parts[512 + t] + fi_b[t];
            xprev = hprev + fmaxf(a, 0.f);
            float partner = __shfl_xor(xprev, 1);
            if ((t & 1) == 0) x2[t >> 1] = packh2(xprev, partner);
            float c0 = xprev * fn_w[t];
            float c1 = xprev * fn_w[256 + t];
#pragma unroll
            for (int off = 32; off >= 1; off >>= 1) {
                c0 += __shfl_down(c0, off);
                c1 += __shfl_down(c1, off);
            }
            if ((t & 63) == 0) { pp[(t >> 6) * 2] = c0; pp[(t >> 6) * 2 + 1] = c1; }
        }
        __syncthreads();
        if (t < 2)
            out[d * 64 + b * 2 + t] =
                tanhf(fn_b[t] + pp[t] + pp[2 + t] + pp[4 + t] + pp[6 + t]);
    }
}

// ---------------------------------------------------------------------------
extern "C" void kernel_launch(void* const* d_in, const int* in_sizes, int n_in,
                              void* d_out, int out_size, void* d_ws, size_t ws_size,
                              hipStream_t stream)
{
    const float* x      = (const float*)d_in[0];
    const float* frames = (const float*)d_in[1];
    const float* cnn_w  = (const float*)d_in[2];
    const float* cnn_b  = (const float*)d_in[3];
    const float* cnn1_w = (const float*)d_in[4];
    const float* cnn1_b = (const float*)d_in[5];
    const float* bn_g   = (const float*)d_in[6];
    const float* bn_b   = (const float*)d_in[7];
    const float* bn_m   = (const float*)d_in[8];
    const float* bn_v   = (const float*)d_in[9];
    const float* a0_w   = (const float*)d_in[10];
    const float* a0_b   = (const float*)d_in[11];
    const float* ai_w   = (const float*)d_in[12];
    const float* ai_b   = (const float*)d_in[13];
    const float* an_w   = (const float*)d_in[14];
    const float* an_b   = (const float*)d_in[15];
    const float* w_ih   = (const float*)d_in[16];
    const float* w_hh   = (const float*)d_in[17];
    const float* b_ih   = (const float*)d_in[18];
    const float* b_hh   = (const float*)d_in[19];
    const float* fi_w   = (const float*)d_in[20];
    const float* fi_b   = (const float*)d_in[21];
    const float* fn_w   = (const float*)d_in[22];
    const float* fn_b   = (const float*)d_in[23];
    float* out = (float*)d_out;

    char* ws = (char*)d_ws;
    u16*   f1     = (u16*)(ws);                   // [0, 28,901,376)
    u16*   B1     = (u16*)(ws + 28901376);        // 884,736
    u16*   B2     = (u16*)(ws + 29786112);        // 663,552
    float* C2     = (float*)(ws + 30449664);      // 6,422,528 (dead after reduce)
    float* fmean  = (float*)(ws + 36872192);      // 131,072
    u32*   whh8   = (u32*)(ws + 37003264);        // 393,216
    u32*   wih8   = (u32*)(ws + 37396480);        // 393,216
    u32*   fi8    = (u32*)(ws + 37789696);        // 131,072
    u32*   zpage  = (u32*)(ws + 37920768);        // 4,096
    // overlap region inside C2 (live only after reduce consumed C2)
    float* gi_pre = (float*)(ws + 30449664);      // 1,572,864
    u16*   wih_hi = (u16*)(ws + 32022528);        // 393,216
    u16*   wih_lo = (u16*)(ws + 32415744);        // 393,216
    u16*   zx_hi  = (u16*)(ws + 32808960);        // 262,144
    u16*   zx_lo  = (u16*)(ws + 33071104);        // 262,144 (ends 33,333,248)
    u16*   fbf    = (u16*)(ws + 37924864);        // 38,535,168 -> needs 76,460,032

    const bool big = ws_size >= 76460032ull;

    prep_kernel<<<big ? 13332 : 3924, 256, 0, stream>>>(
        cnn_w, cnn1_w, w_hh, w_ih, fi_w, frames,
        B1, B2, whh8, wih8, fi8, zpage, fbf);
    if (big) {
        gemm1_v3<<<196 * 3, 256, 0, stream>>>(fbf, B1, cnn_b, f1);
    } else {
        gemm1_patchify<<<196 * 9, 256, 0, stream>>>(frames, B1, cnn_b, f1);
    }
    gemm2_v2<<<392, 256, 0, stream>>>(f1, B2, (const u16*)zpage, C2);
    reduce_kernel<<<128, 256, 0, stream>>>(C2, cnn1_b, bn_g, bn_b, bn_m, bn_v, fmean);
    adapt_prep2_kernel<<<1280, 256, 0, stream>>>(x, fmean, a0_w, a0_b, ai_w, ai_b,
                                                 an_w, an_b, w_ih,
                                                 zx_hi, zx_lo, wih_hi, wih_lo);
    gi_kernel<<<48, 256, 0, stream>>>(zx_hi, zx_lo, wih_hi, wih_lo, b_ih, gi_pre);
    hipFuncSetAttribute((const void*)rnn_stream3,
                        hipFuncAttributeMaxDynamicSharedMemorySize, 147456);
    rnn_stream3<<<32, 768, 147456, stream>>>(gi_pre, (const u32x4*)whh8,
                                             (const u32x4*)wih8, (const u32x4*)fi8,
                                             b_ih, b_hh, fi_b, fn_w, fn_b, out);
}

// Round 7
// 421.032 us; speedup vs baseline: 1.5393x; 1.5393x over previous
//
#include <hip/hip_runtime.h>

typedef unsigned short u16;
typedef unsigned int u32;
typedef __bf16 bf16x8 __attribute__((ext_vector_type(8)));
typedef float f32x4 __attribute__((ext_vector_type(4)));
typedef unsigned short u16x8 __attribute__((ext_vector_type(8)));
typedef unsigned int u32x4 __attribute__((ext_vector_type(4)));
typedef _Float16 v2h __attribute__((ext_vector_type(2)));

__device__ __forceinline__ u16 f2bf(float f) {
    unsigned u = __float_as_uint(f);
    u = (u + 0x7fffu + ((u >> 16) & 1u)) >> 16;
    return (u16)u;
}
__device__ __forceinline__ float bf2f(u16 h) {
    return __uint_as_float((unsigned)h << 16);
}
__device__ __forceinline__ u32 packh2(float a, float b) {
    _Float16 ha = (_Float16)a, hb = (_Float16)b;
    u16 la = __builtin_bit_cast(u16, ha), lb = __builtin_bit_cast(u16, hb);
    return (u32)la | ((u32)lb << 16);
}
__device__ __forceinline__ float dot2acc(u32 w, u32 h, float acc) {
#if __has_builtin(__builtin_amdgcn_fdot2)
    return __builtin_amdgcn_fdot2(__builtin_bit_cast(v2h, w),
                                  __builtin_bit_cast(v2h, h), acc, false);
#else
    v2h wv = __builtin_bit_cast(v2h, w), hv = __builtin_bit_cast(v2h, h);
    return acc + (float)wv.x * (float)hv.x + (float)wv.y * (float)hv.y;
#endif
}
__device__ __forceinline__ float dot8(u32x4 w, u32x4 h, float acc) {
    acc = dot2acc(w.x, h.x, acc);
    acc = dot2acc(w.y, h.y, acc);
    acc = dot2acc(w.z, h.z, acc);
    acc = dot2acc(w.w, h.w, acc);
    return acc;
}
__device__ __forceinline__ void gload_lds16(const void* g, void* l) {
    __builtin_amdgcn_global_load_lds(
        (const __attribute__((address_space(1))) unsigned int*)g,
        (__attribute__((address_space(3))) unsigned int*)l, 16, 0, 0);
}

// ---------------------------------------------------------------------------
// prep+fconv fused. Blocks [0,3924): weight prep; blocks [3924,13332): frames
// fp32->bf16 nt-store (big path only).
// ---------------------------------------------------------------------------
__global__ __launch_bounds__(256) void prep_kernel(
    const float* __restrict__ cnn_w, const float* __restrict__ cnn1_w,
    const float* __restrict__ w_hh, const float* __restrict__ w_ih,
    const float* __restrict__ fi_w, const float* __restrict__ frames,
    u16* __restrict__ B1, u16* __restrict__ B2,
    u32* __restrict__ whh8, u32* __restrict__ wih8, u32* __restrict__ fi8,
    u32* __restrict__ zpage, u16* __restrict__ fbf)
{
    if (blockIdx.x >= 3924) {
        size_t i = ((size_t)(blockIdx.x - 3924) * 256 + threadIdx.x) * 8;
        float4 a = *(const float4*)(frames + i);
        float4 b = *(const float4*)(frames + i + 4);
        u16x8 v = { f2bf(a.x), f2bf(a.y), f2bf(a.z), f2bf(a.w),
                    f2bf(b.x), f2bf(b.y), f2bf(b.z), f2bf(b.w) };
        __builtin_nontemporal_store(v, (u16x8*)(fbf + i));
        return;
    }
    int idx = blockIdx.x * 256 + threadIdx.x;
    if (idx < 442368) { B1[idx] = f2bf(cnn_w[idx]); return; }
    idx -= 442368;
    if (idx < 331776) {
        int n = idx / 5184, rem = idx - n * 5184;
        int off = rem / 576, c = rem - off * 576;
        int dy = off / 3, dx = off - dy * 3;
        B2[idx] = f2bf(cnn1_w[((n * 576 + c) * 3 + dy) * 3 + dx]);
        return;
    }
    idx -= 331776;
    if (idx < 98304) {
        int kb = idx / 3072, r = idx - kb * 3072;
        int o = r >> 2, c = r & 3;
        int kk = kb * 8 + c * 2;
        whh8[idx] = packh2(w_hh[o * 256 + kk], w_hh[o * 256 + kk + 1]);
        return;
    }
    idx -= 98304;
    if (idx < 98304) {
        int kb = idx / 3072, r = idx - kb * 3072;
        int o = r >> 2, c = r & 3;
        int kk = kb * 8 + c * 2;
        wih8[idx] = packh2(w_ih[o * 256 + kk], w_ih[o * 256 + kk + 1]);
        return;
    }
    idx -= 98304;
    if (idx < 32768) {
        int kb = idx / 1024, r = idx - kb * 1024;
        int u = r >> 2, c = r & 3;
        int kk = kb * 8 + c * 2;
        fi8[idx] = packh2(fi_w[u * 256 + kk], fi_w[u * 256 + kk + 1]);
        return;
    }
    idx -= 32768;
    if (idx < 1024) zpage[idx] = 0u;
}

// ---------------------------------------------------------------------------
// GEMM1 v2: patchify conv, BM=128, BN=64, BK=64. grid = 196*9.
// global_load_lds(16B) staging with source-side XOR swizzle.
// ---------------------------------------------------------------------------
__global__ __launch_bounds__(256) void gemm1_v2(
    const u16* __restrict__ fbf, const u16* __restrict__ B1,
    const float* __restrict__ cnn_b, u16* __restrict__ f1)
{
    __shared__ u16 As[128 * 64];
    __shared__ u16 Bs[64 * 64];
    const int t = threadIdx.x, bx = blockIdx.x;
    const int m0 = (bx / 9) * 128, n0 = (bx % 9) * 64;
    const int wave = t >> 6, lane = t & 63;
    const int lm = lane & 15, lq = lane >> 4;

    f32x4 acc[2][4];
#pragma unroll
    for (int i = 0; i < 2; ++i)
#pragma unroll
        for (int q = 0; q < 4; ++q) acc[i][q] = (f32x4){0.f, 0.f, 0.f, 0.f};

    int ac8[4]; size_t abase[4];
#pragma unroll
    for (int i = 0; i < 4; ++i) {
        int s = wave * 256 + i * 64 + lane;
        int row = s >> 3, cc = s & 7;
        ac8[i] = cc ^ (row & 7);
        int m = m0 + row;
        int fr = m / 49, pos = m - fr * 49;
        int py = pos / 7, px = pos - py * 7;
        abase[i] = (size_t)fr * 37632 + py * 1792 + px * 16;
    }
    int bn[2], bc8[2];
#pragma unroll
    for (int i = 0; i < 2; ++i) {
        int s = wave * 128 + i * 64 + lane;
        int n = s >> 3, cc = s & 7;
        bn[i] = n; bc8[i] = cc ^ (n & 7);
    }

    for (int kt = 0; kt < 12; ++kt) {
        const int k0 = kt * 64;
#pragma unroll
        for (int i = 0; i < 4; ++i) {
            int k = k0 + ac8[i] * 8;
            int c = k >> 8, dy = (k >> 4) & 15, dx = k & 15;
            gload_lds16(fbf + abase[i] + c * 12544 + dy * 112 + dx,
                        &As[(wave * 256 + i * 64) * 8]);
        }
#pragma unroll
        for (int i = 0; i < 2; ++i) {
            gload_lds16(B1 + (size_t)(n0 + bn[i]) * 768 + k0 + bc8[i] * 8,
                        &Bs[(wave * 128 + i * 64) * 8]);
        }
        __syncthreads();
#pragma unroll
        for (int s = 0; s < 2; ++s) {
            bf16x8 a[2], b[4];
#pragma unroll
            for (int mi = 0; mi < 2; ++mi) {
                int row = wave * 32 + mi * 16 + lm;
                int c8 = s * 4 + lq;
                a[mi] = *(const bf16x8*)(&As[(row * 8 + (c8 ^ (row & 7))) * 8]);
            }
#pragma unroll
            for (int q = 0; q < 4; ++q) {
                int n = q * 16 + lm;
                int c8 = s * 4 + lq;
                b[q] = *(const bf16x8*)(&Bs[(n * 8 + (c8 ^ (n & 7))) * 8]);
            }
#pragma unroll
            for (int mi = 0; mi < 2; ++mi)
#pragma unroll
                for (int q = 0; q < 4; ++q)
                    acc[mi][q] = __builtin_amdgcn_mfma_f32_16x16x32_bf16(a[mi], b[q], acc[mi][q], 0, 0, 0);
        }
        __syncthreads();
    }
#pragma unroll
    for (int mi = 0; mi < 2; ++mi) {
#pragma unroll
        for (int q = 0; q < 4; ++q) {
            int n = n0 + q * 16 + lm;
            float bias = cnn_b[n];
#pragma unroll
            for (int r = 0; r < 4; ++r) {
                int m = m0 + wave * 32 + mi * 16 + lq * 4 + r;
                __builtin_nontemporal_store(f2bf(acc[mi][q][r] + bias), &f1[(size_t)m * 576 + n]);
            }
        }
    }
}

// ---------------------------------------------------------------------------
// GEMM1 legacy (small ws): VALU-cvt staging from fp32 frames. grid = 196*9.
// ---------------------------------------------------------------------------
__global__ __launch_bounds__(256) void gemm1_patchify(
    const float* __restrict__ frames, const u16* __restrict__ B1,
    const float* __restrict__ cnn_b, u16* __restrict__ f1)
{
    __shared__ u16 As[128 * 64];
    __shared__ u16 Bs[64 * 64];
    const int t = threadIdx.x;
    const int bx = blockIdx.x;
    const int m0 = (bx / 9) * 128;
    const int n0 = (bx % 9) * 64;
    const int wave = t >> 6, lane = t & 63;
    const int lm = lane & 15, lq = lane >> 4;

    f32x4 acc[2][4];
#pragma unroll
    for (int i = 0; i < 2; ++i)
#pragma unroll
        for (int q = 0; q < 4; ++q) acc[i][q] = (f32x4){0.f, 0.f, 0.f, 0.f};

    int arow[4], ac8[4], abase[4];
#pragma unroll
    for (int i = 0; i < 4; ++i) {
        int cid = t + i * 256;
        int row = cid >> 3, c8 = cid & 7;
        int m = m0 + row;
        int fr = m / 49, pos = m - fr * 49;
        int py = pos / 7, px = pos - py * 7;
        arow[i] = row; ac8[i] = c8;
        abase[i] = (fr * 3 * 112 + py * 16) * 112 + px * 16;
    }

    for (int kt = 0; kt < 12; ++kt) {
        const int k0 = kt * 64;
#pragma unroll
        for (int i = 0; i < 4; ++i) {
            int k = k0 + ac8[i] * 8;
            int c = k >> 8, dy = (k >> 4) & 15, dx = k & 15;
            const float* src = frames + abase[i] + (c * 112 + dy) * 112 + dx;
            float4 v0 = *(const float4*)src;
            float4 v1 = *(const float4*)(src + 4);
            u16x8 v = { f2bf(v0.x), f2bf(v0.y), f2bf(v0.z), f2bf(v0.w),
                        f2bf(v1.x), f2bf(v1.y), f2bf(v1.z), f2bf(v1.w) };
            int sidx = arow[i] * 8 + (ac8[i] ^ (arow[i] & 7));
            *(u16x8*)(&As[sidx * 8]) = v;
        }
#pragma unroll
        for (int i = 0; i < 2; ++i) {
            int cid = t + i * 256;
            int n = cid >> 3, c8 = cid & 7;
            u16x8 v = *(const u16x8*)(B1 + (size_t)(n0 + n) * 768 + k0 + c8 * 8);
            int sidx = n * 8 + (c8 ^ (n & 7));
            *(u16x8*)(&Bs[sidx * 8]) = v;
        }
        __syncthreads();
#pragma unroll
        for (int s = 0; s < 2; ++s) {
            bf16x8 a[2], b[4];
#pragma unroll
            for (int mi = 0; mi < 2; ++mi) {
                int row = wave * 32 + mi * 16 + lm;
                int c8 = s * 4 + lq;
                a[mi] = *(const bf16x8*)(&As[(row * 8 + (c8 ^ (row & 7))) * 8]);
            }
#pragma unroll
            for (int q = 0; q < 4; ++q) {
                int n = q * 16 + lm;
                int c8 = s * 4 + lq;
                b[q] = *(const bf16x8*)(&Bs[(n * 8 + (c8 ^ (n & 7))) * 8]);
            }
#pragma unroll
            for (int mi = 0; mi < 2; ++mi)
#pragma unroll
                for (int q = 0; q < 4; ++q)
                    acc[mi][q] = __builtin_amdgcn_mfma_f32_16x16x32_bf16(a[mi], b[q], acc[mi][q], 0, 0, 0);
        }
        __syncthreads();
    }
#pragma unroll
    for (int mi = 0; mi < 2; ++mi) {
#pragma unroll
        for (int q = 0; q < 4; ++q) {
            int n = n0 + q * 16 + lm;
            float bias = cnn_b[n];
#pragma unroll
            for (int r = 0; r < 4; ++r) {
                int m = m0 + wave * 32 + mi * 16 + lq * 4 + r;
                __builtin_nontemporal_store(f2bf(acc[mi][q][r] + bias), &f1[(size_t)m * 576 + n]);
            }
        }
    }
}

// ---------------------------------------------------------------------------
// GEMM2 v2: 3x3 SAME conv, 9-offset implicit GEMM. BM=64, full K=5184.
// global_load_lds staging, zero-page for halo. grid = 392.
// ---------------------------------------------------------------------------
__global__ __launch_bounds__(256) void gemm2_v2(
    const u16* __restrict__ f1, const u16* __restrict__ B2,
    const u16* __restrict__ zpage, float* __restrict__ C2)
{
    __shared__ u16 As[64 * 64];
    __shared__ u16 Bs[64 * 64];
    const int t = threadIdx.x;
    const int m0 = blockIdx.x * 64;
    const int wave = t >> 6, lane = t & 63;
    const int lm = lane & 15, lq = lane >> 4;

    f32x4 acc[4];
#pragma unroll
    for (int q = 0; q < 4; ++q) acc[q] = (f32x4){0.f, 0.f, 0.f, 0.f};

    int ac8[2], afr[2], apy[2], apx[2];
#pragma unroll
    for (int i = 0; i < 2; ++i) {
        int s = wave * 128 + i * 64 + lane;
        int row = s >> 3, cc = s & 7;
        ac8[i] = cc ^ (row & 7);
        int m = m0 + row;
        int fr = m / 49, pos = m - fr * 49;
        int py = pos / 7;
        afr[i] = fr; apy[i] = py; apx[i] = pos - py * 7;
    }
    int bn[2], bc8[2];
#pragma unroll
    for (int i = 0; i < 2; ++i) {
        int s = wave * 128 + i * 64 + lane;
        int n = s >> 3, cc = s & 7;
        bn[i] = n; bc8[i] = cc ^ (n & 7);
    }

    for (int kt = 0; kt < 81; ++kt) {
        int off = kt / 9, cb = kt - off * 9;
        int dy = off / 3, dx = off - dy * 3;
        int c0 = cb * 64;
#pragma unroll
        for (int i = 0; i < 2; ++i) {
            int yy = apy[i] + dy - 1, xx = apx[i] + dx - 1;
            const u16* g = ((unsigned)yy < 7u && (unsigned)xx < 7u)
                ? f1 + ((size_t)(afr[i] * 49 + yy * 7 + xx)) * 576 + c0 + ac8[i] * 8
                : zpage;
            gload_lds16(g, &As[(wave * 128 + i * 64) * 8]);
        }
#pragma unroll
        for (int i = 0; i < 2; ++i) {
            gload_lds16(B2 + (size_t)bn[i] * 5184 + kt * 64 + bc8[i] * 8,
                        &Bs[(wave * 128 + i * 64) * 8]);
        }
        __syncthreads();
#pragma unroll
        for (int s = 0; s < 2; ++s) {
            int row = wave * 16 + lm;
            int c8 = s * 4 + lq;
            bf16x8 a = *(const bf16x8*)(&As[(row * 8 + (c8 ^ (row & 7))) * 8]);
            bf16x8 b[4];
#pragma unroll
            for (int q = 0; q < 4; ++q) {
                int n = q * 16 + lm;
                b[q] = *(const bf16x8*)(&Bs[(n * 8 + (c8 ^ (n & 7))) * 8]);
            }
#pragma unroll
            for (int q = 0; q < 4; ++q)
                acc[q] = __builtin_amdgcn_mfma_f32_16x16x32_bf16(a, b[q], acc[q], 0, 0, 0);
        }
        __syncthreads();
    }
#pragma unroll
    for (int q = 0; q < 4; ++q)
#pragma unroll
        for (int r = 0; r < 4; ++r) {
            int m = m0 + wave * 16 + lq * 4 + r;
            int n = q * 16 + lm;
            __builtin_nontemporal_store(acc[q][r], &C2[(size_t)m * 64 + n]);
        }
}

// ---------------------------------------------------------------------------
// reduce: fmean[bl][ch] = BN( mean_p relu(C2[bl*49+p][ch] + cnn1_b[ch]) )
// ---------------------------------------------------------------------------
__global__ __launch_bounds__(256) void reduce_kernel(
    const float* __restrict__ C2, const float* __restrict__ cnn1_b,
    const float* __restrict__ bn_g, const float* __restrict__ bn_b,
    const float* __restrict__ bn_m, const float* __restrict__ bn_v,
    float* __restrict__ fmean)
{
    int idx = blockIdx.x * 256 + threadIdx.x;
    int bl = idx >> 6, ch = idx & 63;
    float bias = cnn1_b[ch];
    const float* p = C2 + (size_t)bl * 49 * 64 + ch;
    float s = 0.f;
#pragma unroll
    for (int i = 0; i < 49; ++i) s += fmaxf(p[i * 64] + bias, 0.f);
    float mean = s * (1.f / 49.f);
    float inv = bn_g[ch] * rsqrtf(bn_v[ch] + 1e-5f);
    fmean[idx] = (mean - bn_m[ch]) * inv + bn_b[ch];
}

// ---------------------------------------------------------------------------
// adapter + prep2 fused. Blocks [0,512): adapter. Blocks [512,1280): wih hi/lo.
// ---------------------------------------------------------------------------
__global__ __launch_bounds__(256) void adapt_prep2_kernel(
    const float* __restrict__ x, const float* __restrict__ fmean,
    const float* __restrict__ a0_w, const float* __restrict__ a0_b,
    const float* __restrict__ ai_w, const float* __restrict__ ai_b,
    const float* __restrict__ an_w, const float* __restrict__ an_b,
    const float* __restrict__ w_ih,
    u16* __restrict__ zx_hi, u16* __restrict__ zx_lo,
    u16* __restrict__ wih_hi, u16* __restrict__ wih_lo)
{
    const int t = threadIdx.x;
    if (blockIdx.x >= 512) {
        int idx = (blockIdx.x - 512) * 256 + t;
        float v = w_ih[idx];
        u16 hi = f2bf(v);
        wih_hi[idx] = hi;
        wih_lo[idx] = f2bf(v - bf2f(hi));
        return;
    }
    const int bl = blockIdx.x;
    __shared__ float s0[16];
    __shared__ float sf[80];
    if (t < 16) {
        float a = a0_b[t];
        const float* xp = x + bl * 12;
#pragma unroll
        for (int i = 0; i < 12; ++i) a += xp[i] * a0_w[t * 12 + i];
        s0[t] = fmaxf(a, 0.f);
    }
    __syncthreads();
    if (t < 16) {
        float a = ai_b[t];
#pragma unroll
        for (int i = 0; i < 16; ++i) a += s0[i] * ai_w[t * 16 + i];
        sf[t] = s0[t] + fmaxf(a, 0.f);
    } else if (t < 80) {
        sf[t] = fmean[bl * 64 + (t - 16)];
    }
    __syncthreads();
    float a = an_b[t];
#pragma unroll 8
    for (int i = 0; i < 80; ++i) a += sf[i] * an_w[t * 80 + i];
    a = fmaxf(a, 0.f);
    u16 hi = f2bf(a);
    zx_hi[bl * 256 + t] = hi;
    zx_lo[bl * 256 + t] = f2bf(a - bf2f(hi));
}

// ---------------------------------------------------------------------------
// gi_pre = zx @ w_ih^T + b_ih via hi/lo bf16 MFMA. M=512,N=768,K=256. grid=48
// ---------------------------------------------------------------------------
__global__ __launch_bounds__(256) void gi_kernel(
    const u16* __restrict__ zx_hi, const u16* __restrict__ zx_lo,
    const u16* __restrict__ wih_hi, const u16* __restrict__ wih_lo,
    const float* __restrict__ b_ih, float* __restrict__ gi_pre)
{
    __shared__ u16 Ah[128 * 64], Al[128 * 64];
    __shared__ u16 Bh[64 * 64], Bl[64 * 64];
    const int t = threadIdx.x, bx = blockIdx.x;
    const int m0 = (bx / 12) * 128, n0 = (bx % 12) * 64;
    const int wave = t >> 6, lane = t & 63;
    const int lm = lane & 15, lq = lane >> 4;

    f32x4 acc[2][4];
#pragma unroll
    for (int i = 0; i < 2; ++i)
#pragma unroll
        for (int q = 0; q < 4; ++q) acc[i][q] = (f32x4){0.f, 0.f, 0.f, 0.f};

    for (int kt = 0; kt < 4; ++kt) {
        const int k0 = kt * 64;
#pragma unroll
        for (int i = 0; i < 4; ++i) {
            int cid = t + i * 256;
            int row = cid >> 3, c8 = cid & 7;
            size_t src = (size_t)(m0 + row) * 256 + k0 + c8 * 8;
            int sidx = (row * 8 + (c8 ^ (row & 7))) * 8;
            *(u16x8*)(&Ah[sidx]) = *(const u16x8*)(zx_hi + src);
            *(u16x8*)(&Al[sidx]) = *(const u16x8*)(zx_lo + src);
        }
#pragma unroll
        for (int i = 0; i < 2; ++i) {
            int cid = t + i * 256;
            int n = cid >> 3, c8 = cid & 7;
            size_t src = (size_t)(n0 + n) * 256 + k0 + c8 * 8;
            int sidx = (n * 8 + (c8 ^ (n & 7))) * 8;
            *(u16x8*)(&Bh[sidx]) = *(const u16x8*)(wih_hi + src);
            *(u16x8*)(&Bl[sidx]) = *(const u16x8*)(wih_lo + src);
        }
        __syncthreads();
#pragma unroll
        for (int s = 0; s < 2; ++s) {
            bf16x8 ah[2], al[2], bh[4], blv[4];
#pragma unroll
            for (int mi = 0; mi < 2; ++mi) {
                int row = wave * 32 + mi * 16 + lm;
                int c8 = s * 4 + lq;
                int sidx = (row * 8 + (c8 ^ (row & 7))) * 8;
                ah[mi] = *(const bf16x8*)(&Ah[sidx]);
                al[mi] = *(const bf16x8*)(&Al[sidx]);
            }
#pragma unroll
            for (int q = 0; q < 4; ++q) {
                int n = q * 16 + lm;
                int c8 = s * 4 + lq;
                int sidx = (n * 8 + (c8 ^ (n & 7))) * 8;
                bh[q] = *(const bf16x8*)(&Bh[sidx]);
                blv[q] = *(const bf16x8*)(&Bl[sidx]);
            }
#pragma unroll
            for (int mi = 0; mi < 2; ++mi)
#pragma unroll
                for (int q = 0; q < 4; ++q) {
                    acc[mi][q] = __builtin_amdgcn_mfma_f32_16x16x32_bf16(ah[mi], bh[q], acc[mi][q], 0, 0, 0);
                    acc[mi][q] = __builtin_amdgcn_mfma_f32_16x16x32_bf16(ah[mi], blv[q], acc[mi][q], 0, 0, 0);
                    acc[mi][q] = __builtin_amdgcn_mfma_f32_16x16x32_bf16(al[mi], bh[q], acc[mi][q], 0, 0, 0);
                }
        }
        __syncthreads();
    }
#pragma unroll
    for (int q = 0; q < 4; ++q) {
        int n = n0 + q * 16 + lm;
        float bias = b_ih[n];
#pragma unroll
        for (int mi = 0; mi < 2; ++mi)
#pragma unroll
            for (int r = 0; r < 4; ++r) {
                int m = m0 + wave * 32 + mi * 16 + lq * 4 + r;
                gi_pre[(size_t)m * 768 + n] = acc[mi][q][r] + bias;
            }
    }
}

// ---------------------------------------------------------------------------
// rnn_stream4: 32 blocks x 768 threads. whh kb 0..11 pinned in 144KB LDS;
// whh kb 12..19 + wih kb 0..7 pinned in 64 VGPRs (fixed 8-elem arrays, fully
// unrolled const indices -> no spill); remainder streamed with wave rotation.
// Dual accumulators split the fdot2 dep chain. Zero cross-block sync.
// ---------------------------------------------------------------------------
__global__ __launch_bounds__(768) void rnn_stream4(
    const float* __restrict__ gi_pre,
    const u32x4* __restrict__ whh8, const u32x4* __restrict__ wih8,
    const u32x4* __restrict__ fi8,
    const float* __restrict__ b_ih, const float* __restrict__ b_hh,
    const float* __restrict__ fi_b,
    const float* __restrict__ fn_w, const float* __restrict__ fn_b,
    float* __restrict__ out)
{
    extern __shared__ __align__(16) u32 slab[];   // 12*768*16B = 147456 B
    const int b = blockIdx.x, t = threadIdx.x;
    const int wave = t >> 6;
    __shared__ __align__(16) u32 h2[128];
    __shared__ __align__(16) u32 x2[128];
    __shared__ float sA[768];
    __shared__ float sB[256];
    __shared__ float parts[768];
    __shared__ float pp[8];

    // LDS pin: whh kb 0..11
#pragma unroll
    for (int j = 0; j < 12; ++j)
        *(u32x4*)&slab[(j * 768 + t) * 4] = whh8[j * 768 + t];

    // VGPR pin: whh kb 12..19 (32 regs) + wih kb 0..7 (32 regs)
    u32x4 whr[8], wir[8];
#pragma unroll
    for (int j = 0; j < 8; ++j) whr[j] = whh8[(size_t)(12 + j) * 768 + t];
#pragma unroll
    for (int j = 0; j < 8; ++j) wir[j] = wih8[(size_t)j * 768 + t];

    const float bhh = b_hh[t];
    const float bih = b_ih[t];
    float hprev = 0.f;
    if (t < 128) h2[t] = 0u;
    __syncthreads();

    // ===================== encoder: 16 steps =====================
    for (int l = 0; l < 16; ++l) {
        float gi = gi_pre[(size_t)(b * 16 + l) * 768 + t];
        float a0 = 0.f, a1 = 0.f;
        // streamed whh kb 20..31, wave-rotated
#pragma unroll 4
        for (int j = 0; j < 12; ++j) {
            int jj = j + wave; if (jj >= 12) jj -= 12;
            int kb = 20 + jj;
            u32x4 w = whh8[(size_t)kb * 768 + t];
            u32x4 hh = *(const u32x4*)&h2[kb * 4];
            if (j & 1) a1 = dot8(w, hh, a1); else a0 = dot8(w, hh, a0);
        }
        // reg-pinned whh kb 12..19
#pragma unroll
        for (int j = 0; j < 8; ++j) {
            u32x4 hh = *(const u32x4*)&h2[(12 + j) * 4];
            if (j & 1) a1 = dot8(whr[j], hh, a1); else a0 = dot8(whr[j], hh, a0);
        }
        // LDS-pinned whh kb 0..11
#pragma unroll
        for (int j = 0; j < 12; ++j) {
            u32x4 ws = *(const u32x4*)&slab[(j * 768 + t) * 4];
            u32x4 hh = *(const u32x4*)&h2[j * 4];
            if (j & 1) a1 = dot8(ws, hh, a1); else a0 = dot8(ws, hh, a0);
        }
        float ah = a0 + a1;
        if (t < 512) sA[t] = gi + ah + bhh;
        else { sA[t] = gi; sB[t - 512] = ah + bhh; }
        __syncthreads();
        if (t < 256) {
            float r = 1.f / (1.f + expf(-sA[t]));
            float z = 1.f / (1.f + expf(-sA[256 + t]));
            float n = tanhf(sA[512 + t] + r * sB[t]);
            hprev = (1.f - z) * n + z * hprev;
            float partner = __shfl_xor(hprev, 1);
            if ((t & 1) == 0) h2[t >> 1] = packh2(hprev, partner);
        }
        __syncthreads();
    }

    // ===================== decoder: 10 steps =====================
    float xprev = hprev;
    if (t < 128) x2[t] = h2[t];
    __syncthreads();

    for (int d = 0; d < 10; ++d) {
        float a0 = 0.f, a1 = 0.f, x0 = 0.f, x1 = 0.f;
        // streamed whh kb 20..31
#pragma unroll 4
        for (int j = 0; j < 12; ++j) {
            int jj = j + wave; if (jj >= 12) jj -= 12;
            int kb = 20 + jj;
            u32x4 w = whh8[(size_t)kb * 768 + t];
            u32x4 hh = *(const u32x4*)&h2[kb * 4];
            if (j & 1) a1 = dot8(w, hh, a1); else a0 = dot8(w, hh, a0);
        }
        // streamed wih kb 8..31, wave-rotated
#pragma unroll 4
        for (int j = 0; j < 24; ++j) {
            int jj = j + wave * 2; if (jj >= 24) jj -= 24;
            int kb = 8 + jj;
            u32x4 w = wih8[(size_t)kb * 768 + t];
            u32x4 xx = *(const u32x4*)&x2[kb * 4];
            if (j & 1) x1 = dot8(w, xx, x1); else x0 = dot8(w, xx, x0);
        }
        // reg-pinned whh kb 12..19 and wih kb 0..7
#pragma unroll
        for (int j = 0; j < 8; ++j) {
            u32x4 hh = *(const u32x4*)&h2[(12 + j) * 4];
            u32x4 xx = *(const u32x4*)&x2[j * 4];
            if (j & 1) { a1 = dot8(whr[j], hh, a1); x1 = dot8(wir[j], xx, x1); }
            else       { a0 = dot8(whr[j], hh, a0); x0 = dot8(wir[j], xx, x0); }
        }
        // LDS-pinned whh kb 0..11
#pragma unroll
        for (int j = 0; j < 12; ++j) {
            u32x4 ws = *(const u32x4*)&slab[(j * 768 + t) * 4];
            u32x4 hh = *(const u32x4*)&h2[j * 4];
            if (j & 1) a1 = dot8(ws, hh, a1); else a0 = dot8(ws, hh, a0);
        }
        float ah = a0 + a1, ax = x0 + x1;
        if (t < 512) sA[t] = ax + bih + ah + bhh;
        else { sA[t] = ax + bih; sB[t - 512] = ah + bhh; }
        __syncthreads();
        if (t < 256) {
            float r = 1.f / (1.f + expf(-sA[t]));
            float z = 1.f / (1.f + expf(-sA[256 + t]));
            float n = tanhf(sA[512 + t] + r * sB[t]);
            hprev = (1.f - z) * n + z * hprev;
            float partner = __shfl_xor(hprev, 1);
            if ((t & 1) == 0) h2[t >> 1] = packh2(hprev, partner);
        }
        __syncthreads();
        // fi matvec over all 12 waves: unit u = t&255, k-slice s = t>>8
        {
            int u = t & 255, s = t >> 8;
            float afi = 0.f;
            for (int j = s; j < 32; j += 3) {
                u32x4 w = fi8[j * 256 + u];
                u32x4 hh = *(const u32x4*)&h2[j * 4];
                afi = dot8(w, hh, afi);
            }
            parts[t] = afi;
        }
        __syncthreads();
        if (t < 256) {
            float a = parts[t] + parts[256 + t] + parts[512 + t] + fi_b[t];
            xprev = hprev + fmaxf(a, 0.f);
            float partner = __shfl_xor(xprev, 1);
            if ((t & 1) == 0) x2[t >> 1] = packh2(xprev, partner);
            float c0 = xprev * fn_w[t];
            float c1 = xprev * fn_w[256 + t];
#pragma unroll
            for (int off = 32; off >= 1; off >>= 1) {
                c0 += __shfl_down(c0, off);
                c1 += __shfl_down(c1, off);
            }
            if ((t & 63) == 0) { pp[(t >> 6) * 2] = c0; pp[(t >> 6) * 2 + 1] = c1; }
        }
        __syncthreads();
        if (t < 2)
            out[d * 64 + b * 2 + t] =
                tanhf(fn_b[t] + pp[t] + pp[2 + t] + pp[4 + t] + pp[6 + t]);
    }
}

// ---------------------------------------------------------------------------
extern "C" void kernel_launch(void* const* d_in, const int* in_sizes, int n_in,
                              void* d_out, int out_size, void* d_ws, size_t ws_size,
                              hipStream_t stream)
{
    const float* x      = (const float*)d_in[0];
    const float* frames = (const float*)d_in[1];
    const float* cnn_w  = (const float*)d_in[2];
    const float* cnn_b  = (const float*)d_in[3];
    const float* cnn1_w = (const float*)d_in[4];
    const float* cnn1_b = (const float*)d_in[5];
    const float* bn_g   = (const float*)d_in[6];
    const float* bn_b   = (const float*)d_in[7];
    const float* bn_m   = (const float*)d_in[8];
    const float* bn_v   = (const float*)d_in[9];
    const float* a0_w   = (const float*)d_in[10];
    const float* a0_b   = (const float*)d_in[11];
    const float* ai_w   = (const float*)d_in[12];
    const float* ai_b   = (const float*)d_in[13];
    const float* an_w   = (const float*)d_in[14];
    const float* an_b   = (const float*)d_in[15];
    const float* w_ih   = (const float*)d_in[16];
    const float* w_hh   = (const float*)d_in[17];
    const float* b_ih   = (const float*)d_in[18];
    const float* b_hh   = (const float*)d_in[19];
    const float* fi_w   = (const float*)d_in[20];
    const float* fi_b   = (const float*)d_in[21];
    const float* fn_w   = (const float*)d_in[22];
    const float* fn_b   = (const float*)d_in[23];
    float* out = (float*)d_out;

    char* ws = (char*)d_ws;
    u16*   f1     = (u16*)(ws);                   // [0, 28,901,376)
    u16*   B1     = (u16*)(ws + 28901376);        // 884,736
    u16*   B2     = (u16*)(ws + 29786112);        // 663,552
    float* C2     = (float*)(ws + 30449664);      // 6,422,528 (dead after reduce)
    float* fmean  = (float*)(ws + 36872192);      // 131,072
    u32*   whh8   = (u32*)(ws + 37003264);        // 393,216
    u32*   wih8   = (u32*)(ws + 37396480);        // 393,216
    u32*   fi8    = (u32*)(ws + 37789696);        // 131,072
    u32*   zpage  = (u32*)(ws + 37920768);        // 4,096
    // overlap region inside C2 (live only after reduce consumed C2)
    float* gi_pre = (float*)(ws + 30449664);      // 1,572,864
    u16*   wih_hi = (u16*)(ws + 32022528);        // 393,216
    u16*   wih_lo = (u16*)(ws + 32415744);        // 393,216
    u16*   zx_hi  = (u16*)(ws + 32808960);        // 262,144
    u16*   zx_lo  = (u16*)(ws + 33071104);        // 262,144 (ends 33,333,248)
    u16*   fbf    = (u16*)(ws + 37924864);        // 38,535,168 -> needs 76,460,032

    const bool big = ws_size >= 76460032ull;

    prep_kernel<<<big ? 13332 : 3924, 256, 0, stream>>>(
        cnn_w, cnn1_w, w_hh, w_ih, fi_w, frames,
        B1, B2, whh8, wih8, fi8, zpage, fbf);
    if (big) {
        gemm1_v2<<<196 * 9, 256, 0, stream>>>(fbf, B1, cnn_b, f1);
    } else {
        gemm1_patchify<<<196 * 9, 256, 0, stream>>>(frames, B1, cnn_b, f1);
    }
    gemm2_v2<<<392, 256, 0, stream>>>(f1, B2, (const u16*)zpage, C2);
    reduce_kernel<<<128, 256, 0, stream>>>(C2, cnn1_b, bn_g, bn_b, bn_m, bn_v, fmean);
    adapt_prep2_kernel<<<1280, 256, 0, stream>>>(x, fmean, a0_w, a0_b, ai_w, ai_b,
                                                 an_w, an_b, w_ih,
                                                 zx_hi, zx_lo, wih_hi, wih_lo);
    gi_kernel<<<48, 256, 0, stream>>>(zx_hi, zx_lo, wih_hi, wih_lo, b_ih, gi_pre);
    hipFuncSetAttribute((const void*)rnn_stream4,
                        hipFuncAttributeMaxDynamicSharedMemorySize, 147456);
    rnn_stream4<<<32, 768, 147456, stream>>>(gi_pre, (const u32x4*)whh8,
                                             (const u32x4*)wih8, (const u32x4*)fi8,
                                             b_ih, b_hh, fi_b, fn_w, fn_b, out);
}